// Round 1
// baseline (1512.638 us; speedup 1.0000x reference)
//
#include <hip/hip_runtime.h>

#define NN 100000
#define EE 600000
#define DD 128
#define BN_EPS 1e-5f

#define ROWS 64        // rows per MLP block
#define KCH 32         // k-panel staged in LDS
#define LDW 132        // padded leading dim (floats), keeps 16B alignment

// ---------------- Edge aggregation: msg = relu(x[src]+e), atomic scatter-sum ----------------
__global__ __launch_bounds__(256) void edge_aggr(
    const float* __restrict__ x, const int* __restrict__ ei,
    const float* __restrict__ ea, float* __restrict__ aggr)
{
    long long tid = (long long)blockIdx.x * 256 + threadIdx.x;
    int e = (int)(tid >> 5);
    if (e >= EE) return;
    int p = ((int)tid & 31) << 2;          // float offset within D row
    int src = ei[e];
    int dst = ei[EE + e];
    const float4 xv = *(const float4*)(x + (size_t)src * DD + p);
    const float4 ev = *(const float4*)(ea + (size_t)e * DD + p);
    float4 m;
    m.x = fmaxf(xv.x + ev.x, 0.0f);
    m.y = fmaxf(xv.y + ev.y, 0.0f);
    m.z = fmaxf(xv.z + ev.z, 0.0f);
    m.w = fmaxf(xv.w + ev.w, 0.0f);
    float* o = aggr + (size_t)dst * DD + p;
    atomicAdd(o + 0, m.x);
    atomicAdd(o + 1, m.y);
    atomicAdd(o + 2, m.z);
    atomicAdd(o + 3, m.w);
}

// ---------------- Fused row-local MLP ----------------
// Wt[kk][j] = W[j][kb+kk]  (transposed panel, coalesced global reads)
__device__ __forceinline__ void stage_w(const float* __restrict__ W, int kb,
                                        float* __restrict__ Wt, int t)
{
    #pragma unroll
    for (int m = 0; m < 4; ++m) {          // 128*32 floats / (256 thr * 4) = 4
        int lin = m * 1024 + t * 4;
        int j  = lin >> 5;                 // 0..127
        int kk = lin & 31;                 // multiple of 4
        float4 wv = *(const float4*)(W + (size_t)j * DD + kb + kk);
        Wt[(kk + 0) * LDW + j] = wv.x;
        Wt[(kk + 1) * LDW + j] = wv.y;
        Wt[(kk + 2) * LDW + j] = wv.z;
        Wt[(kk + 3) * LDW + j] = wv.w;
    }
}

__device__ __forceinline__ void gemm_chunk(const float* __restrict__ Zs,
                                           const float* __restrict__ Wt,
                                           int rbase, int j0, int kb,
                                           float acc[4][8])
{
    #pragma unroll 2
    for (int k4 = 0; k4 < KCH / 4; ++k4) {
        int k = k4 * 4;
        float4 za[4];
        #pragma unroll
        for (int i = 0; i < 4; ++i)
            za[i] = *(const float4*)&Zs[(rbase + i) * LDW + kb + k];
        #pragma unroll
        for (int kk = 0; kk < 4; ++kk) {
            float4 w0 = *(const float4*)&Wt[(k + kk) * LDW + j0];
            float4 w1 = *(const float4*)&Wt[(k + kk) * LDW + j0 + 4];
            #pragma unroll
            for (int i = 0; i < 4; ++i) {
                float zz = ((const float*)&za[i])[kk];
                acc[i][0] = fmaf(zz, w0.x, acc[i][0]);
                acc[i][1] = fmaf(zz, w0.y, acc[i][1]);
                acc[i][2] = fmaf(zz, w0.z, acc[i][2]);
                acc[i][3] = fmaf(zz, w0.w, acc[i][3]);
                acc[i][4] = fmaf(zz, w1.x, acc[i][4]);
                acc[i][5] = fmaf(zz, w1.y, acc[i][5]);
                acc[i][6] = fmaf(zz, w1.z, acc[i][6]);
                acc[i][7] = fmaf(zz, w1.w, acc[i][7]);
            }
        }
    }
}

__global__ __launch_bounds__(256, 2) void mlp_fused(
    const float* __restrict__ x, const float* __restrict__ aggr,
    const float* __restrict__ epsp,
    const float* __restrict__ W1, const float* __restrict__ b1,
    const float* __restrict__ g1, const float* __restrict__ bt1,
    const float* __restrict__ rm1, const float* __restrict__ rv1,
    const float* __restrict__ W2, const float* __restrict__ b2,
    const float* __restrict__ g2, const float* __restrict__ bt2,
    const float* __restrict__ rm2, const float* __restrict__ rv2,
    float* __restrict__ out)
{
    __shared__ float Zs[ROWS * LDW];   // z panel, then h1 panel
    __shared__ float Wt[KCH * LDW];    // transposed W k-panel

    const int t  = threadIdx.x;
    const int c  = t & 15;             // 16 col-groups * 8 cols
    const int rg = t >> 4;             // 16 row-groups * 4 rows
    const int j0 = c * 8;
    const int rbase = rg * 4;
    const int R0 = blockIdx.x * ROWS;
    const float onepe = 1.0f + epsp[0];

    // ---- stage z = (1+eps)*x + aggr ----
    #pragma unroll
    for (int m = 0; m < 8; ++m) {
        int lin = m * 1024 + t * 4;
        int row = lin >> 7, col = lin & 127;
        float4 zv = make_float4(0.f, 0.f, 0.f, 0.f);
        int grow = R0 + row;
        if (grow < NN) {
            float4 xv = *(const float4*)(x    + (size_t)grow * DD + col);
            float4 av = *(const float4*)(aggr + (size_t)grow * DD + col);
            zv.x = fmaf(onepe, xv.x, av.x);
            zv.y = fmaf(onepe, xv.y, av.y);
            zv.z = fmaf(onepe, xv.z, av.z);
            zv.w = fmaf(onepe, xv.w, av.w);
        }
        *(float4*)&Zs[row * LDW + col] = zv;
    }

    float acc[4][8];
    #pragma unroll
    for (int i = 0; i < 4; ++i)
        #pragma unroll
        for (int u = 0; u < 8; ++u) acc[i][u] = 0.0f;

    // ---- GEMM1: z @ W1^T ----
    stage_w(W1, 0, Wt, t);
    __syncthreads();
    gemm_chunk(Zs, Wt, rbase, j0, 0, acc);
    #pragma unroll
    for (int kb = KCH; kb < DD; kb += KCH) {
        __syncthreads();
        stage_w(W1, kb, Wt, t);
        __syncthreads();
        gemm_chunk(Zs, Wt, rbase, j0, kb, acc);
    }
    __syncthreads();   // all Zs reads done

    // ---- epilogue 1: h1 = relu(bn1(acc + b1)) -> Zs ----
    {
        float s1v[8], o1v[8];
        #pragma unroll
        for (int u = 0; u < 8; ++u) {
            int j = j0 + u;
            float sc = g1[j] * rsqrtf(rv1[j] + BN_EPS);
            s1v[u] = sc;
            o1v[u] = fmaf(b1[j] - rm1[j], sc, bt1[j]);
        }
        #pragma unroll
        for (int i = 0; i < 4; ++i)
            #pragma unroll
            for (int u = 0; u < 8; ++u)
                Zs[(rbase + i) * LDW + j0 + u] =
                    fmaxf(fmaf(acc[i][u], s1v[u], o1v[u]), 0.0f);
    }
    stage_w(W2, 0, Wt, t);
    __syncthreads();

    // ---- GEMM2: h1 @ W2^T ----
    #pragma unroll
    for (int i = 0; i < 4; ++i)
        #pragma unroll
        for (int u = 0; u < 8; ++u) acc[i][u] = 0.0f;

    gemm_chunk(Zs, Wt, rbase, j0, 0, acc);
    #pragma unroll
    for (int kb = KCH; kb < DD; kb += KCH) {
        __syncthreads();
        stage_w(W2, kb, Wt, t);
        __syncthreads();
        gemm_chunk(Zs, Wt, rbase, j0, kb, acc);
    }

    // ---- epilogue 2: out = relu(bn2(x + acc + b2)) ----
    {
        float s2v[8], o2v[8], b2v[8];
        #pragma unroll
        for (int u = 0; u < 8; ++u) {
            int j = j0 + u;
            float sc = g2[j] * rsqrtf(rv2[j] + BN_EPS);
            s2v[u] = sc;
            o2v[u] = fmaf(-rm2[j], sc, bt2[j]);
            b2v[u] = b2[j];
        }
        #pragma unroll
        for (int i = 0; i < 4; ++i) {
            int grow = R0 + rbase + i;
            if (grow >= NN) continue;
            const float* xr = x + (size_t)grow * DD + j0;
            float4 x0 = *(const float4*)xr;
            float4 x1 = *(const float4*)(xr + 4);
            float xs[8] = {x0.x, x0.y, x0.z, x0.w, x1.x, x1.y, x1.z, x1.w};
            float4 r0, r1;
            float r[8];
            #pragma unroll
            for (int u = 0; u < 8; ++u)
                r[u] = fmaxf(fmaf(xs[u] + acc[i][u] + b2v[u], s2v[u], o2v[u]), 0.0f);
            r0 = make_float4(r[0], r[1], r[2], r[3]);
            r1 = make_float4(r[4], r[5], r[6], r[7]);
            float* orow = out + (size_t)grow * DD + j0;
            *(float4*)orow = r0;
            *(float4*)(orow + 4) = r1;
        }
    }
}

extern "C" void kernel_launch(void* const* d_in, const int* in_sizes, int n_in,
                              void* d_out, int out_size, void* d_ws, size_t ws_size,
                              hipStream_t stream)
{
    const float* x   = (const float*)d_in[0];
    const int*   ei  = (const int*)d_in[1];     // [2,E]: row0=src, row1=dst
    const float* ea  = (const float*)d_in[2];
    const float* eps = (const float*)d_in[3];
    const float* W1  = (const float*)d_in[4];
    const float* b1  = (const float*)d_in[5];
    const float* g1  = (const float*)d_in[6];
    const float* bt1 = (const float*)d_in[7];
    const float* rm1 = (const float*)d_in[8];
    const float* rv1 = (const float*)d_in[9];
    const float* W2  = (const float*)d_in[10];
    const float* b2  = (const float*)d_in[11];
    const float* g2  = (const float*)d_in[12];
    const float* bt2 = (const float*)d_in[13];
    const float* rm2 = (const float*)d_in[14];
    const float* rv2 = (const float*)d_in[15];
    float* out  = (float*)d_out;
    float* aggr = (float*)d_ws;                 // N*D f32 = 51.2 MB scratch

    hipMemsetAsync(aggr, 0, (size_t)NN * DD * sizeof(float), stream);

    int eblocks = (EE * 32 + 255) / 256;        // 1 thread per (edge, float4)
    edge_aggr<<<eblocks, 256, 0, stream>>>(x, ei, ea, aggr);

    int mblocks = (NN + ROWS - 1) / ROWS;
    mlp_fused<<<mblocks, 256, 0, stream>>>(x, aggr, eps,
                                           W1, b1, g1, bt1, rm1, rv1,
                                           W2, b2, g2, bt2, rm2, rv2,
                                           out);
}

// Round 2
// 1025.858 us; speedup vs baseline: 1.4745x; 1.4745x over previous
//
#include <hip/hip_runtime.h>

#define NN 100000
#define EE 600000
#define DD 128
#define BN_EPS 1e-5f

#define ROWS 64        // rows per MLP block
#define KCH 32         // k-panel staged in LDS
#define LDW 132        // Zs leading dim (floats)
#define WLD 145        // Wt leading dim (odd -> conflict-free staging writes)
#define NBLK ((NN + 1023) / 1024)   // scan blocks

// physical column in Wt: pad 1 float every 8 cols -> 16 distinct banks for j0=c*8
__device__ __forceinline__ int wpad(int j) { return j + (j >> 3); }

// ================= edge phase: CSR build + gather =================

__global__ __launch_bounds__(256) void hist_dst(const int* __restrict__ ei,
                                                int* __restrict__ cnt)
{
    int e = blockIdx.x * 256 + threadIdx.x;
    if (e < EE) atomicAdd(&cnt[ei[EE + e]], 1);
}

__global__ __launch_bounds__(256) void scan_blocksum(const int* __restrict__ cnt,
                                                     int* __restrict__ partials)
{
    __shared__ int sm[256];
    int b = blockIdx.x, t = threadIdx.x;
    int base = b * 1024 + t * 4;
    int s = 0;
    #pragma unroll
    for (int q = 0; q < 4; ++q) { int i = base + q; if (i < NN) s += cnt[i]; }
    sm[t] = s; __syncthreads();
    for (int off = 128; off > 0; off >>= 1) {
        if (t < off) sm[t] += sm[t + off];
        __syncthreads();
    }
    if (t == 0) partials[b] = sm[0];
}

__global__ void scan_partials(int* __restrict__ partials)
{
    if (threadIdx.x == 0) {
        int run = 0;
        for (int i = 0; i < NBLK; ++i) { int v = partials[i]; partials[i] = run; run += v; }
    }
}

__global__ __launch_bounds__(256) void scan_write(const int* __restrict__ cnt,
                                                  const int* __restrict__ partials,
                                                  int* __restrict__ cursor)
{
    __shared__ int sm[256];
    int b = blockIdx.x, t = threadIdx.x;
    int base = b * 1024 + t * 4;
    int v[4]; int s = 0;
    #pragma unroll
    for (int q = 0; q < 4; ++q) {
        int i = base + q;
        v[q] = (i < NN) ? cnt[i] : 0;
        s += v[q];
    }
    sm[t] = s; __syncthreads();
    int val = s;
    for (int off = 1; off < 256; off <<= 1) {
        int add = (t >= off) ? sm[t - off] : 0;
        __syncthreads();
        val += add; sm[t] = val;
        __syncthreads();
    }
    int ex = val - s + partials[b];       // exclusive prefix for this thread's 4
    #pragma unroll
    for (int q = 0; q < 4; ++q) {
        int i = base + q;
        if (i < NN) cursor[i] = ex;
        ex += v[q];
    }
}

__global__ __launch_bounds__(256) void scatter_eids(const int* __restrict__ ei,
                                                    int* __restrict__ cursor,
                                                    int* __restrict__ eids)
{
    int e = blockIdx.x * 256 + threadIdx.x;
    if (e < EE) {
        int d = ei[EE + e];
        int p = atomicAdd(&cursor[d], 1);
        eids[p] = e;
    }
}

// one 32-lane group per node; lane p owns float4 at col p*4
__global__ __launch_bounds__(256) void gather_z(
    const float* __restrict__ x, const int* __restrict__ ei,
    const float* __restrict__ ea, const int* __restrict__ cnt,
    const int* __restrict__ cursor, const int* __restrict__ eids,
    const float* __restrict__ epsp, float* __restrict__ z)
{
    int g = blockIdx.x * 8 + (threadIdx.x >> 5);
    if (g >= NN) return;
    int p = (threadIdx.x & 31) * 4;
    int deg = cnt[g];
    int end = cursor[g];          // after scatter: cursor[v] = end offset
    int off = end - deg;

    float4 acc = make_float4(0.f, 0.f, 0.f, 0.f);
    int e = 0, s = 0;
    if (deg > 0) { e = eids[off]; s = ei[e]; }
    for (int i = 0; i < deg; ++i) {
        int e2 = 0, s2 = 0;
        if (i + 1 < deg) { e2 = eids[off + i + 1]; s2 = ei[e2]; }   // prefetch chain
        float4 xv = *(const float4*)(x + (size_t)s * DD + p);
        float4 ev = *(const float4*)(ea + (size_t)e * DD + p);
        acc.x += fmaxf(xv.x + ev.x, 0.f);
        acc.y += fmaxf(xv.y + ev.y, 0.f);
        acc.z += fmaxf(xv.z + ev.z, 0.f);
        acc.w += fmaxf(xv.w + ev.w, 0.f);
        e = e2; s = s2;
    }
    float onepe = 1.f + epsp[0];
    float4 xv = *(const float4*)(x + (size_t)g * DD + p);
    float4 zv;
    zv.x = fmaf(onepe, xv.x, acc.x);
    zv.y = fmaf(onepe, xv.y, acc.y);
    zv.z = fmaf(onepe, xv.z, acc.z);
    zv.w = fmaf(onepe, xv.w, acc.w);
    *(float4*)(z + (size_t)g * DD + p) = zv;
}

// ================= fused row-local MLP =================

// load one K-panel of W into 4 float4 regs (coalesced: 8 lanes per row chunk)
__device__ __forceinline__ void wload(const float* __restrict__ W, int kb, int t,
                                      float4 wr[4])
{
    #pragma unroll
    for (int m = 0; m < 4; ++m) {
        int lin = m * 1024 + t * 4;
        int j  = lin >> 5;
        int kk = lin & 31;
        wr[m] = *(const float4*)(W + (size_t)j * DD + kb + kk);
    }
}

__device__ __forceinline__ void wstore(float* __restrict__ Wt, int t,
                                       const float4 wr[4])
{
    #pragma unroll
    for (int m = 0; m < 4; ++m) {
        int lin = m * 1024 + t * 4;
        int j  = lin >> 5;
        int kk = lin & 31;
        int jp = wpad(j);
        Wt[(kk + 0) * WLD + jp] = wr[m].x;
        Wt[(kk + 1) * WLD + jp] = wr[m].y;
        Wt[(kk + 2) * WLD + jp] = wr[m].z;
        Wt[(kk + 3) * WLD + jp] = wr[m].w;
    }
}

__device__ __forceinline__ void gemm_chunk(const float* __restrict__ Zs,
                                           const float* __restrict__ Wt,
                                           int rbase, int j0p, int kb,
                                           float acc[4][8])
{
    #pragma unroll 2
    for (int k4 = 0; k4 < KCH / 4; ++k4) {
        int k = k4 * 4;
        float4 za[4];
        #pragma unroll
        for (int i = 0; i < 4; ++i)
            za[i] = *(const float4*)&Zs[(rbase + i) * LDW + kb + k];
        #pragma unroll
        for (int kk = 0; kk < 4; ++kk) {
            const float* wrow = &Wt[(k + kk) * WLD + j0p];
            float4 w0 = *(const float4*)wrow;
            float4 w1 = *(const float4*)(wrow + 4);
            #pragma unroll
            for (int i = 0; i < 4; ++i) {
                float zz = ((const float*)&za[i])[kk];
                acc[i][0] = fmaf(zz, w0.x, acc[i][0]);
                acc[i][1] = fmaf(zz, w0.y, acc[i][1]);
                acc[i][2] = fmaf(zz, w0.z, acc[i][2]);
                acc[i][3] = fmaf(zz, w0.w, acc[i][3]);
                acc[i][4] = fmaf(zz, w1.x, acc[i][4]);
                acc[i][5] = fmaf(zz, w1.y, acc[i][5]);
                acc[i][6] = fmaf(zz, w1.z, acc[i][6]);
                acc[i][7] = fmaf(zz, w1.w, acc[i][7]);
            }
        }
    }
}

__global__ __launch_bounds__(256, 2) void mlp_fused(
    const float* __restrict__ z, const float* __restrict__ x,
    const float* __restrict__ W1, const float* __restrict__ b1,
    const float* __restrict__ g1, const float* __restrict__ bt1,
    const float* __restrict__ rm1, const float* __restrict__ rv1,
    const float* __restrict__ W2, const float* __restrict__ b2,
    const float* __restrict__ g2, const float* __restrict__ bt2,
    const float* __restrict__ rm2, const float* __restrict__ rv2,
    float* __restrict__ out)
{
    __shared__ float Zs[ROWS * LDW];
    __shared__ float Wt[2][KCH * WLD];

    const int t  = threadIdx.x;
    const int c  = t & 15;
    const int rg = t >> 4;
    const int j0 = c * 8;
    const int j0p = wpad(j0);
    const int rbase = rg * 4;
    const int R0 = blockIdx.x * ROWS;

    // ---- stage z panel ----
    #pragma unroll
    for (int m = 0; m < 8; ++m) {
        int lin = m * 1024 + t * 4;
        int row = lin >> 7, col = lin & 127;
        int grow = R0 + row;
        float4 zv = make_float4(0.f, 0.f, 0.f, 0.f);
        if (grow < NN) zv = *(const float4*)(z + (size_t)grow * DD + col);
        *(float4*)&Zs[row * LDW + col] = zv;
    }

    float4 wr[4];
    wload(W1, 0, t, wr);
    wstore(Wt[0], t, wr);
    wload(W1, KCH, t, wr);          // prefetch panel 1
    __syncthreads();                 // Zs + Wt[0] ready

    float acc[4][8];
    #pragma unroll
    for (int i = 0; i < 4; ++i)
        #pragma unroll
        for (int u = 0; u < 8; ++u) acc[i][u] = 0.0f;

    // ---- GEMM1 (double-buffered W panels, 1 sync per panel) ----
    #pragma unroll
    for (int p = 0; p < 4; ++p) {
        gemm_chunk(Zs, Wt[p & 1], rbase, j0p, p * KCH, acc);
        wstore(Wt[(p + 1) & 1], t, wr);
        if (p < 2)      wload(W1, (p + 2) * KCH, t, wr);
        else if (p == 2) wload(W2, 0, t, wr);
        else             wload(W2, KCH, t, wr);
        __syncthreads();
    }

    // ---- epilogue 1: h1 = relu(bn1(acc + b1)) -> Zs ----
    {
        #pragma unroll
        for (int u = 0; u < 8; u += 4) {
            float s1v[4], o1v[4];
            #pragma unroll
            for (int q = 0; q < 4; ++q) {
                int j = j0 + u + q;
                float sc = g1[j] * rsqrtf(rv1[j] + BN_EPS);
                s1v[q] = sc;
                o1v[q] = fmaf(b1[j] - rm1[j], sc, bt1[j]);
            }
            #pragma unroll
            for (int i = 0; i < 4; ++i) {
                float4 h;
                h.x = fmaxf(fmaf(acc[i][u + 0], s1v[0], o1v[0]), 0.0f);
                h.y = fmaxf(fmaf(acc[i][u + 1], s1v[1], o1v[1]), 0.0f);
                h.z = fmaxf(fmaf(acc[i][u + 2], s1v[2], o1v[2]), 0.0f);
                h.w = fmaxf(fmaf(acc[i][u + 3], s1v[3], o1v[3]), 0.0f);
                *(float4*)&Zs[(rbase + i) * LDW + j0 + u] = h;
            }
        }
    }
    __syncthreads();                 // h1 visible; Wt[0] already holds W2 panel 0

    #pragma unroll
    for (int i = 0; i < 4; ++i)
        #pragma unroll
        for (int u = 0; u < 8; ++u) acc[i][u] = 0.0f;

    // ---- GEMM2 ----
    #pragma unroll
    for (int p = 0; p < 4; ++p) {
        gemm_chunk(Zs, Wt[p & 1], rbase, j0p, p * KCH, acc);
        if (p < 3) {
            wstore(Wt[(p + 1) & 1], t, wr);
            if (p < 2) wload(W2, (p + 2) * KCH, t, wr);
            __syncthreads();
        }
    }

    // ---- epilogue 2: out = relu(bn2(x + acc + b2)) ----
    {
        float s2v[8], o2v[8];
        #pragma unroll
        for (int u = 0; u < 8; ++u) {
            int j = j0 + u;
            float sc = g2[j] * rsqrtf(rv2[j] + BN_EPS);
            s2v[u] = sc;
            o2v[u] = fmaf(b2[j] - rm2[j], sc, bt2[j]);
        }
        #pragma unroll
        for (int i = 0; i < 4; ++i) {
            int grow = R0 + rbase + i;
            if (grow >= NN) continue;
            const float* xr = x + (size_t)grow * DD + j0;
            float4 x0 = *(const float4*)xr;
            float4 x1 = *(const float4*)(xr + 4);
            float xs[8] = {x0.x, x0.y, x0.z, x0.w, x1.x, x1.y, x1.z, x1.w};
            float r[8];
            #pragma unroll
            for (int u = 0; u < 8; ++u)
                r[u] = fmaxf(fmaf(xs[u] + acc[i][u], s2v[u], o2v[u]), 0.0f);
            float* orow = out + (size_t)grow * DD + j0;
            *(float4*)orow       = make_float4(r[0], r[1], r[2], r[3]);
            *(float4*)(orow + 4) = make_float4(r[4], r[5], r[6], r[7]);
        }
    }
}

extern "C" void kernel_launch(void* const* d_in, const int* in_sizes, int n_in,
                              void* d_out, int out_size, void* d_ws, size_t ws_size,
                              hipStream_t stream)
{
    const float* x   = (const float*)d_in[0];
    const int*   ei  = (const int*)d_in[1];     // [2,E]: row0=src, row1=dst
    const float* ea  = (const float*)d_in[2];
    const float* eps = (const float*)d_in[3];
    const float* W1  = (const float*)d_in[4];
    const float* b1  = (const float*)d_in[5];
    const float* g1  = (const float*)d_in[6];
    const float* bt1 = (const float*)d_in[7];
    const float* rm1 = (const float*)d_in[8];
    const float* rv1 = (const float*)d_in[9];
    const float* W2  = (const float*)d_in[10];
    const float* b2  = (const float*)d_in[11];
    const float* g2  = (const float*)d_in[12];
    const float* bt2 = (const float*)d_in[13];
    const float* rm2 = (const float*)d_in[14];
    const float* rv2 = (const float*)d_in[15];
    float* out = (float*)d_out;

    // workspace layout
    float* z        = (float*)d_ws;                     // N*D floats (51.2 MB)
    int*   cnt      = (int*)(z + (size_t)NN * DD);      // N
    int*   cursor   = cnt + NN;                         // N
    int*   partials = cursor + NN;                      // NBLK (<=128)
    int*   eids     = partials + 128;                   // E

    hipMemsetAsync(cnt, 0, NN * sizeof(int), stream);

    int eblocks = (EE + 255) / 256;
    hist_dst    <<<eblocks, 256, 0, stream>>>(ei, cnt);
    scan_blocksum<<<NBLK, 256, 0, stream>>>(cnt, partials);
    scan_partials<<<1, 64, 0, stream>>>(partials);
    scan_write  <<<NBLK, 256, 0, stream>>>(cnt, partials, cursor);
    scatter_eids<<<eblocks, 256, 0, stream>>>(ei, cursor, eids);

    gather_z<<<(NN + 7) / 8, 256, 0, stream>>>(x, ei, ea, cnt, cursor, eids, eps, z);

    int mblocks = (NN + ROWS - 1) / ROWS;
    mlp_fused<<<mblocks, 256, 0, stream>>>(z, x,
                                           W1, b1, g1, bt1, rm1, rv1,
                                           W2, b2, g2, bt2, rm2, rv2,
                                           out);
}

// Round 3
// 691.278 us; speedup vs baseline: 2.1882x; 1.4840x over previous
//
#include <hip/hip_runtime.h>

#define NN 100000
#define EE 600000
#define DD 128
#define BN_EPS 1e-5f

#define ROWS 64                       // rows per MLP block
#define ZLD 136                       // Z LDS stride in bf16 (136*2B=272B -> 17r bank spread)
#define WLD2 40                       // W panel LDS stride in bf16 (80B rows, 16B-aligned)
#define NBLK ((NN + 1023) / 1024)     // scan blocks

typedef __attribute__((ext_vector_type(8))) __bf16 bf16x8;
typedef __attribute__((ext_vector_type(4))) float  f32x4;

__device__ __forceinline__ unsigned bf16h(float f) {      // RNE bf16 bits
    unsigned u = __float_as_uint(f);
    return (u + 0x7FFFu + ((u >> 16) & 1u)) >> 16;
}
__device__ __forceinline__ float bf16tof(unsigned h) {
    return __uint_as_float(h << 16);
}

// ================= edge phase: CSR build =================

__global__ __launch_bounds__(256) void hist_dst(const int* __restrict__ ei,
                                                int* __restrict__ cnt)
{
    int e = blockIdx.x * 256 + threadIdx.x;
    if (e < EE) atomicAdd(&cnt[ei[EE + e]], 1);
}

__global__ __launch_bounds__(256) void scan_blocksum(const int* __restrict__ cnt,
                                                     int* __restrict__ partials)
{
    __shared__ int sm[256];
    int b = blockIdx.x, t = threadIdx.x;
    int base = b * 1024 + t * 4;
    int s = 0;
    #pragma unroll
    for (int q = 0; q < 4; ++q) { int i = base + q; if (i < NN) s += cnt[i]; }
    sm[t] = s; __syncthreads();
    for (int off = 128; off > 0; off >>= 1) {
        if (t < off) sm[t] += sm[t + off];
        __syncthreads();
    }
    if (t == 0) partials[b] = sm[0];
}

__global__ __launch_bounds__(128) void scan_partials(int* __restrict__ p)
{
    __shared__ int sm[128];
    int t = threadIdx.x;
    int v = (t < NBLK) ? p[t] : 0;
    int val = v;
    sm[t] = v; __syncthreads();
    for (int off = 1; off < 128; off <<= 1) {
        int add = (t >= off) ? sm[t - off] : 0;
        __syncthreads();
        val += add; sm[t] = val;
        __syncthreads();
    }
    if (t < NBLK) p[t] = val - v;     // exclusive
}

__global__ __launch_bounds__(256) void scan_write(const int* __restrict__ cnt,
                                                  const int* __restrict__ partials,
                                                  int* __restrict__ cursor)
{
    __shared__ int sm[256];
    int b = blockIdx.x, t = threadIdx.x;
    int base = b * 1024 + t * 4;
    int v[4]; int s = 0;
    #pragma unroll
    for (int q = 0; q < 4; ++q) {
        int i = base + q;
        v[q] = (i < NN) ? cnt[i] : 0;
        s += v[q];
    }
    sm[t] = s; __syncthreads();
    int val = s;
    for (int off = 1; off < 256; off <<= 1) {
        int add = (t >= off) ? sm[t - off] : 0;
        __syncthreads();
        val += add; sm[t] = val;
        __syncthreads();
    }
    int ex = val - s + partials[b];
    #pragma unroll
    for (int q = 0; q < 4; ++q) {
        int i = base + q;
        if (i < NN) cursor[i] = ex;
        ex += v[q];
    }
}

__global__ __launch_bounds__(256) void scatter_eids(const int* __restrict__ ei,
                                                    int* __restrict__ cursor,
                                                    int* __restrict__ eids)
{
    int e = blockIdx.x * 256 + threadIdx.x;
    if (e < EE) {
        int d = ei[EE + e];
        int p = atomicAdd(&cursor[d], 1);
        eids[p] = e;
    }
}

// ================= W hi/lo bf16 split (once per launch) =================
// out layout: [W1h | W1l | W2h | W2l], each 128*128 bf16 row-major
__global__ __launch_bounds__(256) void w_split(const float* __restrict__ W1,
                                               const float* __restrict__ W2,
                                               unsigned short* __restrict__ o)
{
    int i = blockIdx.x * 256 + threadIdx.x;
    if (i < DD * DD) {
        float f = W1[i];
        unsigned h = bf16h(f);
        o[i] = (unsigned short)h;
        o[DD * DD + i] = (unsigned short)bf16h(f - bf16tof(h));
        f = W2[i];
        h = bf16h(f);
        o[2 * DD * DD + i] = (unsigned short)h;
        o[3 * DD * DD + i] = (unsigned short)bf16h(f - bf16tof(h));
    }
}

// ================= gather: z = (1+eps)x + sum relu(x[src]+ea), split to bf16 h/l ===========
__global__ __launch_bounds__(256) void gather_z(
    const float* __restrict__ x, const int* __restrict__ ei,
    const float* __restrict__ ea, const int* __restrict__ cnt,
    const int* __restrict__ cursor, const int* __restrict__ eids,
    const float* __restrict__ epsp,
    unsigned short* __restrict__ zh, unsigned short* __restrict__ zl)
{
    int g = blockIdx.x * 8 + (threadIdx.x >> 5);
    if (g >= NN) return;
    int p4 = (threadIdx.x & 31) * 4;

    int deg = cnt[g];
    int off = cursor[g] - deg;        // cursor[g] = end after scatter

    float4 acc = make_float4(0.f, 0.f, 0.f, 0.f);
    int e0 = 0, s0 = 0, e1 = 0, s1 = 0;
    if (deg > 0) { e0 = eids[off];     s0 = ei[e0]; }
    if (deg > 1) { e1 = eids[off + 1]; s1 = ei[e1]; }
    for (int i = 0; i < deg; ++i) {
        int e2 = 0, s2 = 0;
        if (i + 2 < deg) { e2 = eids[off + i + 2]; s2 = ei[e2]; }
        const float4 xv = *(const float4*)(x  + (size_t)s0 * DD + p4);
        const float4 ev = *(const float4*)(ea + (size_t)e0 * DD + p4);
        acc.x += fmaxf(xv.x + ev.x, 0.f);
        acc.y += fmaxf(xv.y + ev.y, 0.f);
        acc.z += fmaxf(xv.z + ev.z, 0.f);
        acc.w += fmaxf(xv.w + ev.w, 0.f);
        e0 = e1; s0 = s1; e1 = e2; s1 = s2;
    }
    float onepe = 1.f + epsp[0];
    const float4 xv = *(const float4*)(x + (size_t)g * DD + p4);
    float zv[4];
    zv[0] = fmaf(onepe, xv.x, acc.x);
    zv[1] = fmaf(onepe, xv.y, acc.y);
    zv[2] = fmaf(onepe, xv.z, acc.z);
    zv[3] = fmaf(onepe, xv.w, acc.w);

    unsigned hb[4], lb[4];
    #pragma unroll
    for (int q = 0; q < 4; ++q) {
        hb[q] = bf16h(zv[q]);
        lb[q] = bf16h(zv[q] - bf16tof(hb[q]));
    }
    uint2 hp, lp;
    hp.x = hb[0] | (hb[1] << 16); hp.y = hb[2] | (hb[3] << 16);
    lp.x = lb[0] | (lb[1] << 16); lp.y = lb[2] | (lb[3] << 16);
    *(uint2*)(zh + (size_t)g * DD + p4) = hp;
    *(uint2*)(zl + (size_t)g * DD + p4) = lp;
}

// ================= MFMA MLP =================
// Each wave owns a 16-row M-tile (wave-private Z panel rows); 8 N-tiles of 16 cols.
// 3-term split: acc += zh*wh + zl*wh + zh*wl.

struct WRegs { uint4 h0, h1, l0, l1; };

__device__ __forceinline__ void wload_panel(const unsigned short* __restrict__ Wbh,
                                            const unsigned short* __restrict__ Wbl,
                                            int kc, int t, WRegs& R)
{
    int j0 = t >> 2, k0 = (t & 3) * 8;            // chunk 0: rows 0..63
    R.h0 = *(const uint4*)(Wbh + (size_t)j0 * DD + kc + k0);
    R.l0 = *(const uint4*)(Wbl + (size_t)j0 * DD + kc + k0);
    int j1 = j0 + 64;                             // chunk 1: rows 64..127
    R.h1 = *(const uint4*)(Wbh + (size_t)j1 * DD + kc + k0);
    R.l1 = *(const uint4*)(Wbl + (size_t)j1 * DD + kc + k0);
}

__device__ __forceinline__ void wstore_panel(unsigned short* __restrict__ Bh,
                                             unsigned short* __restrict__ Bl,
                                             int t, const WRegs& R)
{
    int j0 = t >> 2, k0 = (t & 3) * 8;
    *(uint4*)&Bh[j0 * WLD2 + k0] = R.h0;
    *(uint4*)&Bl[j0 * WLD2 + k0] = R.l0;
    int j1 = j0 + 64;
    *(uint4*)&Bh[j1 * WLD2 + k0] = R.h1;
    *(uint4*)&Bl[j1 * WLD2 + k0] = R.l1;
}

__global__ __launch_bounds__(256, 2) void mlp_mfma(
    const unsigned short* __restrict__ zh, const unsigned short* __restrict__ zl,
    const float* __restrict__ x,
    const unsigned short* __restrict__ Wsp,          // [W1h|W1l|W2h|W2l]
    const float* __restrict__ b1,
    const float* __restrict__ g1, const float* __restrict__ bt1,
    const float* __restrict__ rm1, const float* __restrict__ rv1,
    const float* __restrict__ b2,
    const float* __restrict__ g2, const float* __restrict__ bt2,
    const float* __restrict__ rm2, const float* __restrict__ rv2,
    float* __restrict__ out)
{
    __shared__ unsigned short Zh[ROWS * ZLD];
    __shared__ unsigned short Zl[ROWS * ZLD];
    __shared__ unsigned short Wh[2][DD * WLD2];
    __shared__ unsigned short Wl[2][DD * WLD2];

    const int t    = threadIdx.x;
    const int w    = t >> 6;          // wave 0..3
    const int lane = t & 63;
    const int l15  = lane & 15;
    const int kg   = lane >> 4;       // 0..3
    const int R0   = blockIdx.x * ROWS;

    const unsigned short* W1h = Wsp;
    const unsigned short* W1l = Wsp + DD * DD;
    const unsigned short* W2h = Wsp + 2 * DD * DD;
    const unsigned short* W2l = Wsp + 3 * DD * DD;

    // ---- stage Z rows (wave-private: rows w*16 .. w*16+15) ----
    #pragma unroll
    for (int q = 0; q < 4; ++q) {
        int chunk = q * 64 + lane;            // 0..255 : 16B chunks of 16x128 bf16
        int r16 = chunk >> 4;
        int ko  = (chunk & 15) * 8;
        int grow = R0 + w * 16 + r16;
        uint4 vh = make_uint4(0u, 0u, 0u, 0u), vl = vh;
        if (grow < NN) {
            vh = *(const uint4*)(zh + (size_t)grow * DD + ko);
            vl = *(const uint4*)(zl + (size_t)grow * DD + ko);
        }
        *(uint4*)&Zh[(w * 16 + r16) * ZLD + ko] = vh;
        *(uint4*)&Zl[(w * 16 + r16) * ZLD + ko] = vl;
    }

    // ---- W pipeline prologue ----
    WRegs R[2];
    wload_panel(W1h, W1l, 0, t, R[0]);
    wstore_panel(Wh[0], Wl[0], t, R[0]);     // panel 0 -> buf 0
    wload_panel(W1h, W1l, 32, t, R[1]);      // panel 1 -> regs
    __syncthreads();

    f32x4 acc[8];
    #pragma unroll
    for (int jt = 0; jt < 8; ++jt) acc[jt] = (f32x4){0.f, 0.f, 0.f, 0.f};

    // panels 0..3 = W1 k-chunks, 4..7 = W2 k-chunks
    #pragma unroll
    for (int p = 0; p < 8; ++p) {
        const int buf = p & 1;
        // issue global loads for panel p+2 early (independent)
        if (p < 6) {
            if (p < 2) wload_panel(W1h, W1l, (p + 2) * 32, t, R[p & 1]);
            else       wload_panel(W2h, W2l, (p - 2) * 32, t, R[p & 1]);
        }

        const int kbase = (p & 3) * 32 + kg * 8;
        const bf16x8 ah = *reinterpret_cast<const bf16x8*>(&Zh[(w * 16 + l15) * ZLD + kbase]);
        const bf16x8 al = *reinterpret_cast<const bf16x8*>(&Zl[(w * 16 + l15) * ZLD + kbase]);

        #pragma unroll
        for (int jt = 0; jt < 8; ++jt) {
            const int wo = (jt * 16 + l15) * WLD2 + kg * 8;
            const bf16x8 bh = *reinterpret_cast<const bf16x8*>(&Wh[buf][wo]);
            const bf16x8 bl = *reinterpret_cast<const bf16x8*>(&Wl[buf][wo]);
            acc[jt] = __builtin_amdgcn_mfma_f32_16x16x32_bf16(ah, bh, acc[jt], 0, 0, 0);
            acc[jt] = __builtin_amdgcn_mfma_f32_16x16x32_bf16(al, bh, acc[jt], 0, 0, 0);
            acc[jt] = __builtin_amdgcn_mfma_f32_16x16x32_bf16(ah, bl, acc[jt], 0, 0, 0);
        }

        if (p == 3) {
            // epilogue 1: h1 = relu(bn1(acc+b1)) -> restage (wave-private rows, no barrier)
            #pragma unroll
            for (int jt = 0; jt < 8; ++jt) {
                int j = jt * 16 + l15;
                float sc = g1[j] * rsqrtf(rv1[j] + BN_EPS);
                float of = fmaf(b1[j] - rm1[j], sc, bt1[j]);
                #pragma unroll
                for (int r = 0; r < 4; ++r) {
                    int row = w * 16 + kg * 4 + r;
                    float h = fmaxf(fmaf(acc[jt][r], sc, of), 0.f);
                    unsigned hh = bf16h(h);
                    Zh[row * ZLD + j] = (unsigned short)hh;
                    Zl[row * ZLD + j] = (unsigned short)bf16h(h - bf16tof(hh));
                }
                acc[jt] = (f32x4){0.f, 0.f, 0.f, 0.f};
            }
        }

        if (p < 7) {
            wstore_panel(Wh[(p + 1) & 1], Wl[(p + 1) & 1], t, R[(p + 1) & 1]);
            __syncthreads();
        }
    }

    // ---- epilogue 2: out = relu(bn2(x + acc + b2)) ----
    #pragma unroll
    for (int jt = 0; jt < 8; ++jt) {
        int j = jt * 16 + l15;
        float sc = g2[j] * rsqrtf(rv2[j] + BN_EPS);
        float of = fmaf(b2[j] - rm2[j], sc, bt2[j]);
        #pragma unroll
        for (int r = 0; r < 4; ++r) {
            int grow = R0 + w * 16 + kg * 4 + r;
            if (grow < NN) {
                float xv = x[(size_t)grow * DD + j];
                out[(size_t)grow * DD + j] = fmaxf(fmaf(xv + acc[jt][r], sc, of), 0.f);
            }
        }
    }
}

extern "C" void kernel_launch(void* const* d_in, const int* in_sizes, int n_in,
                              void* d_out, int out_size, void* d_ws, size_t ws_size,
                              hipStream_t stream)
{
    const float* x   = (const float*)d_in[0];
    const int*   ei  = (const int*)d_in[1];     // [2,E]: row0=src, row1=dst
    const float* ea  = (const float*)d_in[2];
    const float* eps = (const float*)d_in[3];
    const float* W1  = (const float*)d_in[4];
    const float* b1  = (const float*)d_in[5];
    const float* g1  = (const float*)d_in[6];
    const float* bt1 = (const float*)d_in[7];
    const float* rm1 = (const float*)d_in[8];
    const float* rv1 = (const float*)d_in[9];
    const float* W2  = (const float*)d_in[10];
    const float* b2  = (const float*)d_in[11];
    const float* g2  = (const float*)d_in[12];
    const float* bt2 = (const float*)d_in[13];
    const float* rm2 = (const float*)d_in[14];
    const float* rv2 = (const float*)d_in[15];
    float* out = (float*)d_out;

    // workspace layout
    unsigned short* zh  = (unsigned short*)d_ws;            // N*D bf16
    unsigned short* zl  = zh + (size_t)NN * DD;             // N*D bf16
    int* cnt      = (int*)(zl + (size_t)NN * DD);           // N
    int* cursor   = cnt + NN;                               // N
    int* partials = cursor + NN;                            // 128
    int* eids     = partials + 128;                         // E
    unsigned short* wsp = (unsigned short*)(eids + EE);     // 4 * 128*128 bf16

    hipMemsetAsync(cnt, 0, NN * sizeof(int), stream);

    int eblocks = (EE + 255) / 256;
    w_split     <<<(DD * DD + 255) / 256, 256, 0, stream>>>(W1, W2, wsp);
    hist_dst    <<<eblocks, 256, 0, stream>>>(ei, cnt);
    scan_blocksum<<<NBLK, 256, 0, stream>>>(cnt, partials);
    scan_partials<<<1, 128, 0, stream>>>(partials);
    scan_write  <<<NBLK, 256, 0, stream>>>(cnt, partials, cursor);
    scatter_eids<<<eblocks, 256, 0, stream>>>(ei, cursor, eids);

    gather_z<<<(NN + 7) / 8, 256, 0, stream>>>(x, ei, ea, cnt, cursor, eids, eps, zh, zl);

    int mblocks = (NN + ROWS - 1) / ROWS;
    mlp_mfma<<<mblocks, 256, 0, stream>>>(zh, zl, x, wsp,
                                          b1, g1, bt1, rm1, rv1,
                                          b2, g2, bt2, rm2, rv2,
                                          out);
}